// Round 14
// baseline (848.436 us; speedup 1.0000x reference)
//
#include <hip/hip_runtime.h>
#include <hip/hip_bf16.h>

typedef __bf16 bf16x8 __attribute__((ext_vector_type(8)));
typedef float f32x4 __attribute__((ext_vector_type(4)));
typedef float f32x2 __attribute__((ext_vector_type(2)));
typedef unsigned short u16x8 __attribute__((ext_vector_type(8)));

#define N_DRUG   10000
#define N_CELL   20000
#define NEDGE    1280000
#define D_DRUG   384
#define D_CELL   3504
#define D_CELL_P 3520
#define BATCH    4096

typedef unsigned int u32_g __attribute__((address_space(1)));
typedef unsigned int u32_l __attribute__((address_space(3)));

__device__ __forceinline__ void gld_lds16(const void* g, void* l) {
  __builtin_amdgcn_global_load_lds((const u32_g*)g, (u32_l*)l, 16, 0, 0);
}

__device__ __forceinline__ ushort f2bf(float f) {
  union { float f; unsigned u; } v; v.f = f;
  unsigned r = v.u + 0x7fffu + ((v.u >> 16) & 1u);
  return (ushort)(r >> 16);
}
__device__ __forceinline__ float bf2f(ushort h) {
  union { unsigned u; float f; } v; v.u = ((unsigned)h) << 16;
  return v.f;
}

#define S_BARRIER() asm volatile("s_barrier" ::: "memory")
#define LGKMCNT0()  asm volatile("s_waitcnt lgkmcnt(0)" ::: "memory")
#define VMCNT6()    asm volatile("s_waitcnt vmcnt(6)" ::: "memory")
#define VMCNT0()    asm volatile("s_waitcnt vmcnt(0)" ::: "memory")

// ---------------- fused conversions ----------------

__global__ __launch_bounds__(256) void conv_xd(const float* __restrict__ x,
                                               const float* __restrict__ dx,
                                               const int* __restrict__ drug,
                                               ushort* __restrict__ xb,
                                               ushort* __restrict__ adb) {
  const int CXB = (N_CELL * (D_CELL_P / 8)) / 256;   // 34375
  if (blockIdx.x < CXB) {
    int idx = blockIdx.x * 256 + threadIdx.x;
    const int CH = D_CELL_P / 8;
    int r = idx / CH, c8 = (idx % CH) * 8;
    if (r >= N_CELL) return;
    ushort4 a, b;
    if (c8 < D_CELL) {
      const float* p = x + (size_t)r * D_CELL + c8;
      float4 v0 = *(const float4*)p;
      float4 v1 = *(const float4*)(p + 4);
      a = make_ushort4(f2bf(v0.x), f2bf(v0.y), f2bf(v0.z), f2bf(v0.w));
      b = make_ushort4(f2bf(v1.x), f2bf(v1.y), f2bf(v1.z), f2bf(v1.w));
    } else {
      a = make_ushort4(0,0,0,0); b = make_ushort4(0,0,0,0);
    }
    ushort* q = xb + (size_t)r * D_CELL_P + c8;
    *(ushort4*)q = a; *(ushort4*)(q + 4) = b;
  } else {
    int idx = (blockIdx.x - CXB) * 256 + threadIdx.x;
    int r = idx / 48, c8 = (idx % 48) * 8;
    int g = drug[r];
    const float* p = dx + (size_t)g * D_DRUG + c8;
    float4 v0 = *(const float4*)p, v1 = *(const float4*)(p + 4);
    ushort4 a = make_ushort4(f2bf(v0.x), f2bf(v0.y), f2bf(v0.z), f2bf(v0.w));
    ushort4 b = make_ushort4(f2bf(v1.x), f2bf(v1.y), f2bf(v1.z), f2bf(v1.w));
    ushort* q = adb + (size_t)r * D_DRUG + c8;
    *(ushort4*)q = a; *(ushort4*)(q + 4) = b;
  }
}

__global__ __launch_bounds__(256) void conv_wt_all(
    const float* __restrict__ c1_lW, const float* __restrict__ c1_rW,
    const float* __restrict__ c2_lW, const float* __restrict__ c2_rW,
    const float* __restrict__ demb_W, const float* __restrict__ reg_W1,
    const float* __restrict__ reg_W2,
    ushort* __restrict__ W1t, ushort* __restrict__ W2t, ushort* __restrict__ Wdt,
    ushort* __restrict__ W1rt, ushort* __restrict__ W2rt) {
  int id = blockIdx.x;
  const float *L, *R; int nL, N, Kin, Kp, nkx; ushort* out; int base;
  if (id < 7040)      { base = 0;    L = c1_lW;  R = c1_rW;  nL = 1024; N = 2048; Kin = 3504; Kp = 3520; out = W1t;  nkx = 110; }
  else if (id < 7552) { base = 7040; L = c2_lW;  R = c2_rW;  nL = 256;  N = 512;  Kin = 1024; Kp = 1024; out = W2t;  nkx = 32; }
  else if (id < 7600) { base = 7552; L = demb_W; R = demb_W; nL = 128;  N = 128;  Kin = 384;  Kp = 384;  out = Wdt;  nkx = 12; }
  else if (id < 7744) { base = 7600; L = reg_W1; R = reg_W1; nL = 384;  N = 384;  Kin = 384;  Kp = 384;  out = W1rt; nkx = 12; }
  else                { base = 7744; L = reg_W2; R = reg_W2; nL = 384;  N = 384;  Kin = 384;  Kp = 384;  out = W2rt; nkx = 12; }
  int lid = id - base;
  int k0 = (lid % nkx) * 32, n0 = (lid / nkx) * 32;

  __shared__ float tile[32][33];
  int t = threadIdx.x;
  int tn = t & 31, tk = t >> 5;
  #pragma unroll
  for (int p = 0; p < 4; ++p) {
    int k = k0 + tk + p * 8, n = n0 + tn;
    float v = 0.f;
    if (k < Kin) v = (n < nL) ? L[(size_t)k * nL + n] : R[(size_t)k * (N - nL) + (n - nL)];
    tile[tk + p * 8][tn] = v;
  }
  __syncthreads();
  int wk = t & 31, wn = t >> 5;
  #pragma unroll
  for (int p = 0; p < 4; ++p) {
    int n = n0 + wn + p * 8, k = k0 + wk;
    out[(size_t)n * Kp + k] = f2bf(tile[wk][wn + p * 8]);
  }
}

// ---------------- CSR build ----------------

__global__ void deg_mark(const int* __restrict__ dst, int* __restrict__ deg,
                         const int* __restrict__ cell, int* __restrict__ mark) {
  if (blockIdx.x < 2048) {
    for (int e = blockIdx.x * 256 + threadIdx.x; e < NEDGE; e += 2048 * 256)
      atomicAdd(&deg[dst[e]], 1);
  } else {
    int b = (blockIdx.x - 2048) * 256 + threadIdx.x;
    if (b < BATCH) mark[cell[b]] = 1;
  }
}

__global__ __launch_bounds__(1024) void scan_kernel(const int* __restrict__ deg,
                                                    int* __restrict__ rowptr,
                                                    int* __restrict__ cursor, int n) {
  __shared__ int wsum[16];
  __shared__ int carry_s;
  int t = threadIdx.x, wave = t >> 6, lane = t & 63;
  if (t == 0) carry_s = 0;
  __syncthreads();
  for (int base = 0; base < n; base += 1024) {
    int x = (base + t < n) ? deg[base + t] : 0;
    int v = x;
    #pragma unroll
    for (int off = 1; off < 64; off <<= 1) {
      int u = __shfl_up(v, off, 64);
      if (lane >= off) v += u;
    }
    if (lane == 63) wsum[wave] = v;
    __syncthreads();
    if (wave == 0 && lane < 16) {
      int w = wsum[lane];
      #pragma unroll
      for (int off = 1; off < 16; off <<= 1) {
        int u = __shfl_up(w, off, 64);
        if (lane >= off) w += u;
      }
      wsum[lane] = w;
    }
    __syncthreads();
    int wpre = (wave == 0) ? 0 : wsum[wave - 1];
    int incl = v + wpre;
    int carry = carry_s;
    if (base + t < n) { int ex = carry + incl - x; rowptr[base + t] = ex; cursor[base + t] = ex; }
    __syncthreads();
    if (t == 1023) carry_s = carry + incl;
    __syncthreads();
  }
  if (t == 0) rowptr[n] = carry_s;
}

__global__ void bucket_kernel(const int* __restrict__ src, const int* __restrict__ dst,
                              int* __restrict__ cursor, int* __restrict__ srcs, int n) {
  for (int e = blockIdx.x * blockDim.x + threadIdx.x; e < n; e += gridDim.x * blockDim.x) {
    int p = atomicAdd(&cursor[dst[e]], 1);
    srcs[p] = src[e];
  }
}

// ---------------- 256x128 GEMM, 16x16x32, 2-phase, vmcnt(6)/K-tile ----------------
// BM=256, BN=128, BK=64; 8 waves = 4(wr) x 2(wc), wave tile 64x64, acc[4][4].
// LDS 96KB dbuf: A chunks 0-31, B chunks 32-47 (16x32 XOR-swizzled chunks).
// Per K-tile: P1 {read af both kc + bf kc0, 16 MFMA kc0};
// P2 {read bf kc1, lgkm(0), barrier, stage A0/A1/B (kt+2) -> buf b,
//     16 MFMA kc1, vmcnt(6), barrier}. Grid: x = col tile (fastest), y = row.
// EPI 0 (GEMM1): col<1024 -> fp8 (agg); col>=1024 -> bf16 (root).
// EPI 1 (GEMM2): bf16 [M,512].
template <int EPI, int K>
__global__ __launch_bounds__(512, 2) void gemm2p(const ushort* __restrict__ A,
                                                 const ushort* __restrict__ Bt,
                                                 float* __restrict__ outF,
                                                 ushort* __restrict__ outB,
                                                 int M) {
  constexpr int NK = K / 64;
  __shared__ ushort lds[2][48][512];   // 96 KB

  const int t = threadIdx.x;
  const int wid = t >> 6, lane = t & 63;
  const int wr = wid >> 1, wc = wid & 1;
  const int brow = blockIdx.y * 256, bcol = blockIdx.x * 128;
  const int fr = lane & 15, kgi = lane >> 4;
  const int slot8 = (fr * 4 + (kgi ^ ((fr >> 1) & 3))) * 8;
  const int srow = lane >> 2;
  const int gsw = ((lane & 3) ^ ((lane >> 3) & 3)) * 8;

  f32x4 acc[4][4];
  #pragma unroll
  for (int m = 0; m < 4; ++m)
    #pragma unroll
    for (int n = 0; n < 4; ++n) acc[m][n] = f32x4{0.f, 0.f, 0.f, 0.f};

  auto stage = [&](int b, int h, int kt) {   // h: 0=A rows 0-127, 1=A rows 128-255, 2=B
    const int k0 = kt * 64;
    #pragma unroll
    for (int j = 0; j < 2; ++j) {
      int c = j * 8 + wid;                   // 0..15 within region
      int kc = c & 1;
      if (h < 2) {
        int r16 = h * 8 + (c >> 1);
        int row = brow + r16 * 16 + srow;
        row = row < M ? row : M - 1;
        gld_lds16(A + (size_t)row * K + k0 + kc * 32 + gsw, &lds[b][r16 * 2 + kc][0]);
      } else {
        int r16b = c >> 1;
        int row = bcol + r16b * 16 + srow;
        gld_lds16(Bt + (size_t)row * K + k0 + kc * 32 + gsw, &lds[b][32 + r16b * 2 + kc][0]);
      }
    }
  };

  // prologue: tile0 (6 loads) + tile1 (6 loads); wait tile0.
  stage(0, 0, 0); stage(0, 1, 0); stage(0, 2, 0);
  stage(1, 0, 1); stage(1, 1, 1); stage(1, 2, 1);
  VMCNT6();
  S_BARRIER();

  for (int kt = 0; kt < NK; ++kt) {
    const int b = kt & 1;
    const bool dr = (kt + 2 >= NK);
    bf16x8 af[4][2], bf[4][2];

    // ---- P1: all af + bf kc0; MFMA kc0 ----
    #pragma unroll
    for (int m = 0; m < 4; ++m) {
      af[m][0] = *(const bf16x8*)&lds[b][(wr * 4 + m) * 2 + 0][slot8];
      af[m][1] = *(const bf16x8*)&lds[b][(wr * 4 + m) * 2 + 1][slot8];
    }
    #pragma unroll
    for (int n = 0; n < 4; ++n)
      bf[n][0] = *(const bf16x8*)&lds[b][32 + (wc * 4 + n) * 2 + 0][slot8];
    __builtin_amdgcn_s_setprio(1);
    #pragma unroll
    for (int m = 0; m < 4; ++m)
      #pragma unroll
      for (int n = 0; n < 4; ++n)
        acc[m][n] = __builtin_amdgcn_mfma_f32_16x16x32_bf16(af[m][0], bf[n][0], acc[m][n], 0, 0, 0);
    __builtin_amdgcn_s_setprio(0);

    // ---- P2: bf kc1; drain reads; stage kt+2; MFMA kc1 ----
    #pragma unroll
    for (int n = 0; n < 4; ++n)
      bf[n][1] = *(const bf16x8*)&lds[b][32 + (wc * 4 + n) * 2 + 1][slot8];
    LGKMCNT0();
    S_BARRIER();                       // all waves done reading buf b
    if (!dr) { stage(b, 0, kt + 2); stage(b, 1, kt + 2); stage(b, 2, kt + 2); }
    __builtin_amdgcn_s_setprio(1);
    #pragma unroll
    for (int m = 0; m < 4; ++m)
      #pragma unroll
      for (int n = 0; n < 4; ++n)
        acc[m][n] = __builtin_amdgcn_mfma_f32_16x16x32_bf16(af[m][1], bf[n][1], acc[m][n], 0, 0, 0);
    __builtin_amdgcn_s_setprio(0);
    if (dr) { VMCNT0(); } else { VMCNT6(); }
    S_BARRIER();                       // buf (kt+1)&1 resident
  }

  unsigned char* o8 = (unsigned char*)outF;   // EPI 0: fp8 agg operand
  const int fq = lane >> 4;
  #pragma unroll
  for (int m = 0; m < 4; ++m)
    #pragma unroll
    for (int n = 0; n < 4; ++n)
      #pragma unroll
      for (int j = 0; j < 4; ++j) {
        int row = brow + wr * 64 + m * 16 + fq * 4 + j;
        int col = bcol + wc * 64 + n * 16 + fr;
        if (row < M) {
          float v = acc[m][n][j];
          if constexpr (EPI == 0) {
            if (col < 1024) {
              int p = __builtin_amdgcn_cvt_pk_fp8_f32(v, v, 0, false);
              o8[(size_t)row * 1024 + col] = (unsigned char)(p & 0xff);
            } else {
              outB[(size_t)row * 1024 + (col - 1024)] = f2bf(v);
            }
          } else {
            outB[(size_t)row * 512 + col] = f2bf(v);
          }
        }
      }
}

// ---------------- 128x128 GEMM (small GEMMs) ----------------
template <int EPI>
__global__ __launch_bounds__(256) void gemm_bt(const ushort* __restrict__ A,
                                               const ushort* __restrict__ Bt,
                                               float* __restrict__ outF,
                                               ushort* __restrict__ outB,
                                               const float* __restrict__ bias,
                                               int M, int N, int K, int ldc) {
  __shared__ ushort ldsA[128 * 32];
  __shared__ ushort ldsB[128 * 32];
  const int t = threadIdx.x;
  const int wave = t >> 6, lane = t & 63;
  const int brow = blockIdx.y * 128;
  const int bcol = blockIdx.x * 128;
  const int wr = wave >> 1, wc = wave & 1;

  f32x4 acc[4][4];
  #pragma unroll
  for (int m = 0; m < 4; ++m)
    #pragma unroll
    for (int n = 0; n < 4; ++n) acc[m][n] = f32x4{0.f, 0.f, 0.f, 0.f};

  const int srow = lane >> 2;
  const int gsw  = ((lane & 3) ^ ((lane >> 3) & 3)) * 8;
  const int nk = K >> 5;

  const int fr = lane & 15;
  const int kgi = lane >> 4;
  const int slot = (fr * 4 + (kgi ^ ((fr >> 1) & 3))) * 8;

  for (int kt = 0; kt < nk; ++kt) {
    const int k0 = kt * 32;
    #pragma unroll
    for (int i = 0; i < 2; ++i) {
      int c = i * 4 + wave;
      int arow = brow + c * 16 + srow;
      arow = arow < M ? arow : M - 1;
      gld_lds16(A + (size_t)arow * K + k0 + gsw, ldsA + c * 512);
      int brB = bcol + c * 16 + srow;
      gld_lds16(Bt + (size_t)brB * K + k0 + gsw, ldsB + c * 512);
    }
    __syncthreads();
    bf16x8 af[4], bf[4];
    #pragma unroll
    for (int m = 0; m < 4; ++m) af[m] = *(const bf16x8*)(ldsA + (wr * 4 + m) * 512 + slot);
    #pragma unroll
    for (int n = 0; n < 4; ++n) bf[n] = *(const bf16x8*)(ldsB + (wc * 4 + n) * 512 + slot);
    #pragma unroll
    for (int m = 0; m < 4; ++m)
      #pragma unroll
      for (int n = 0; n < 4; ++n)
        acc[m][n] = __builtin_amdgcn_mfma_f32_16x16x32_bf16(af[m], bf[n], acc[m][n], 0, 0, 0);
    __syncthreads();
  }

  const int fq = lane >> 4;
  #pragma unroll
  for (int m = 0; m < 4; ++m) {
    #pragma unroll
    for (int n = 0; n < 4; ++n) {
      #pragma unroll
      for (int j = 0; j < 4; ++j) {
        int row = brow + wr * 64 + m * 16 + fq * 4 + j;
        int col = bcol + wc * 64 + n * 16 + fr;
        if (row < M) {
          float v = acc[m][n][j];
          if constexpr (EPI == 0) {
            outF[(size_t)row * ldc + col] = v;
          } else if constexpr (EPI == 2) {
            v += bias[col];
            v = fmaxf(v, 0.f);
            outB[(size_t)row * ldc + col] = f2bf(v);
          } else {
            v += bias[col];
            v = v > 0.f ? v : expm1f(v);
            outB[(size_t)row * ldc + col] = f2bf(v);
          }
        }
      }
    }
  }
}

// ---------------- aggregation ----------------

__global__ __launch_bounds__(256) void agg1_c1(const unsigned char* __restrict__ Yl8,
                                               const ushort* __restrict__ Yrb,
                                               const float* __restrict__ lb,
                                               const int* __restrict__ rowptr,
                                               const int* __restrict__ srcs,
                                               ushort* __restrict__ c1b) {
  const int b = blockIdx.x, t = threadIdx.x;
  const int s = b & 7;                       // column slice (XCD-pinned)
  const int i = (b >> 3) * 4 + (t >> 6);     // node
  const int lane = t & 63;
  const int eg = lane >> 3, c8 = lane & 7;   // 8 edge groups x 16-col chunks
  const int s0 = rowptr[i], s1 = rowptr[i + 1];
  const unsigned char* base = Yl8 + s * 128 + c8 * 16;

  float a[16];
  #pragma unroll
  for (int k = 0; k < 16; ++k) a[k] = 0.f;

  auto accum = [&](uint4 v) {
    const unsigned* w = (const unsigned*)&v;
    #pragma unroll
    for (int q = 0; q < 4; ++q) {
      f32x2 lo = __builtin_amdgcn_cvt_pk_f32_fp8(w[q], false);
      f32x2 hi = __builtin_amdgcn_cvt_pk_f32_fp8(w[q], true);
      a[q * 4 + 0] += lo.x; a[q * 4 + 1] += lo.y;
      a[q * 4 + 2] += hi.x; a[q * 4 + 3] += hi.y;
    }
  };

  int e = s0 + eg;
  for (; e + 8 < s1; e += 16) {
    uint4 vA = *(const uint4*)(base + (size_t)srcs[e] * 1024);
    uint4 vB = *(const uint4*)(base + (size_t)srcs[e + 8] * 1024);
    accum(vA); accum(vB);
  }
  for (; e < s1; e += 8) {
    uint4 v = *(const uint4*)(base + (size_t)srcs[e] * 1024);
    accum(v);
  }
  #pragma unroll
  for (int k = 0; k < 16; ++k) {
    a[k] += __shfl_xor(a[k], 8, 64);
    a[k] += __shfl_xor(a[k], 16, 64);
    a[k] += __shfl_xor(a[k], 32, 64);
  }
  if (eg == 0) {
    float inv = 1.0f / fmaxf((float)(s1 - s0), 1.0f);
    size_t off = (size_t)i * 1024 + s * 128 + c8 * 16;
    u16x8 r0 = *(const u16x8*)(Yrb + off);
    u16x8 r1 = *(const u16x8*)(Yrb + off + 8);
    u16x8 o0, o1;
    #pragma unroll
    for (int k = 0; k < 8; ++k) {
      float v0 = a[k] * inv + lb[s * 128 + c8 * 16 + k] + bf2f(r0[k]);
      float v1 = a[k + 8] * inv + lb[s * 128 + c8 * 16 + 8 + k] + bf2f(r1[k]);
      o0[k] = f2bf(fmaxf(v0, 0.f));
      o1[k] = f2bf(fmaxf(v1, 0.f));
    }
    *(u16x8*)(c1b + off) = o0;
    *(u16x8*)(c1b + off + 8) = o1;
  }
}

__global__ __launch_bounds__(256) void agg2_c2(const ushort* __restrict__ Zb,
                                               const float* __restrict__ lb,
                                               const int* __restrict__ rowptr,
                                               const int* __restrict__ srcs,
                                               const int* __restrict__ mark,
                                               ushort* __restrict__ c2v) {
  int i = blockIdx.x;
  if (!mark[i]) return;
  __shared__ float red[4][32][8];
  int t = threadIdx.x;
  int sub = t >> 5, c = t & 31;
  int wave = t >> 6, lane = t & 63;
  int s0 = rowptr[i], s1 = rowptr[i + 1];
  float a[8] = {0.f, 0.f, 0.f, 0.f, 0.f, 0.f, 0.f, 0.f};
  int e = s0 + sub;
  for (; e + 8 < s1; e += 16) {
    int sA = srcs[e], sB = srcs[e + 8];
    u16x8 vA = *(const u16x8*)(Zb + (size_t)sA * 512 + c * 8);
    u16x8 vB = *(const u16x8*)(Zb + (size_t)sB * 512 + c * 8);
    #pragma unroll
    for (int k = 0; k < 8; ++k) a[k] += bf2f(vA[k]) + bf2f(vB[k]);
  }
  for (; e < s1; e += 8) {
    int src = srcs[e];
    u16x8 v = *(const u16x8*)(Zb + (size_t)src * 512 + c * 8);
    #pragma unroll
    for (int k = 0; k < 8; ++k) a[k] += bf2f(v[k]);
  }
  #pragma unroll
  for (int k = 0; k < 8; ++k) a[k] += __shfl_xor(a[k], 32, 64);
  if (lane < 32) {
    #pragma unroll
    for (int k = 0; k < 8; ++k) red[wave][lane][k] = a[k];
  }
  __syncthreads();
  if (t < 32) {
    float inv = 1.0f / fmaxf((float)(s1 - s0), 1.0f);
    u16x8 r = *(const u16x8*)(Zb + (size_t)i * 512 + 256 + t * 8);
    u16x8 o;
    #pragma unroll
    for (int k = 0; k < 8; ++k) {
      float sum = red[0][t][k] + red[1][t][k] + red[2][t][k] + red[3][t][k];
      float v = sum * inv + lb[t * 8 + k] + bf2f(r[k]);
      o[k] = f2bf(fmaxf(v, 0.f));
    }
    *(u16x8*)(c2v + (size_t)i * 256 + t * 8) = o;
  }
}

__global__ __launch_bounds__(256) void xcat2(const ushort* __restrict__ c2v,
                                             const int* __restrict__ cell,
                                             ushort* __restrict__ xcat) {
  int idx = blockIdx.x * 256 + threadIdx.x;
  int b = idx >> 6, q = idx & 63;
  ushort4 v = *(const ushort4*)(c2v + (size_t)cell[b] * 256 + q * 4);
  *(ushort4*)(xcat + (size_t)b * 384 + 128 + q * 4) = v;
}

__global__ __launch_bounds__(256) void final_k(const ushort* __restrict__ h2,
                                               const float* __restrict__ W3,
                                               const float* __restrict__ b3,
                                               float* __restrict__ out) {
  int row = blockIdx.x * 4 + (threadIdx.x >> 6);
  int lane = threadIdx.x & 63;
  const ushort* p = h2 + (size_t)row * 384;
  float s = 0.f;
  #pragma unroll
  for (int k = lane; k < 384; k += 64) s += bf2f(p[k]) * W3[k];
  #pragma unroll
  for (int off = 32; off; off >>= 1) s += __shfl_xor(s, off, 64);
  if (lane == 0) out[row] = s + b3[0];
}

// ---------------- launch ----------------

extern "C" void kernel_launch(void* const* d_in, const int* in_sizes, int n_in,
                              void* d_out, int out_size, void* d_ws, size_t ws_size,
                              hipStream_t stream) {
  (void)in_sizes; (void)n_in; (void)out_size; (void)ws_size;
  const int*   drug   = (const int*)  d_in[0];
  const int*   cell   = (const int*)  d_in[1];
  const float* drug_x = (const float*)d_in[2];
  const float* cell_x = (const float*)d_in[3];
  const int*   edges  = (const int*)  d_in[4];
  const float* demb_W = (const float*)d_in[5];
  const float* demb_b = (const float*)d_in[6];
  const float* c1_lW  = (const float*)d_in[7];
  const float* c1_lb  = (const float*)d_in[8];
  const float* c1_rW  = (const float*)d_in[9];
  const float* c2_lW  = (const float*)d_in[10];
  const float* c2_lb  = (const float*)d_in[11];
  const float* c2_rW  = (const float*)d_in[12];
  const float* reg_W1 = (const float*)d_in[13];
  const float* reg_b1 = (const float*)d_in[14];
  const float* reg_W2 = (const float*)d_in[15];
  const float* reg_b2 = (const float*)d_in[16];
  const float* reg_W3 = (const float*)d_in[17];
  const float* reg_b3 = (const float*)d_in[18];
  float* out = (float*)d_out;

  char* ws = (char*)d_ws;
  size_t off = 0;
  auto alloc = [&](size_t b) { size_t o = off; off += (b + 255) & ~(size_t)255; return o; };
  size_t oXB  = alloc((size_t)N_CELL * D_CELL_P * 2);
  size_t oW1T = alloc((size_t)2048 * D_CELL_P * 2);
  size_t oYL8 = alloc((size_t)N_CELL * 1024);          // fp8 agg operand
  size_t oYRB = alloc((size_t)N_CELL * 1024 * 2);      // bf16 root operand
  size_t oW2T = alloc((size_t)512 * 1024 * 2);
  size_t oSRC = alloc((size_t)NEDGE * 4);
  size_t oDEG = alloc((size_t)N_CELL * 4);             // deg (memset with mrk)
  size_t oMRK = alloc((size_t)N_CELL * 4);             // adjacent to deg
  size_t oRPT = alloc((size_t)(N_CELL + 1) * 4);
  size_t oCUR = alloc((size_t)N_CELL * 4);
  size_t oADB = alloc((size_t)BATCH * D_DRUG * 2);
  size_t oWDT = alloc((size_t)128 * 384 * 2);
  size_t oXC  = alloc((size_t)BATCH * 384 * 2);
  size_t oW1R = alloc((size_t)384 * 384 * 2);
  size_t oW2R = alloc((size_t)384 * 384 * 2);
  size_t oH1  = alloc((size_t)BATCH * 384 * 2);
  size_t oH2  = alloc((size_t)BATCH * 384 * 2);

  ushort* Xb   = (ushort*)(ws + oXB);
  ushort* c1b  = (ushort*)(ws + oXB);                   // after GEMM1, Xb dead
  ushort* Zb   = (ushort*)(ws + oXB + 40960000);        // bf16 [20000 x 512]
  ushort* c2v  = (ushort*)(ws + oXB + 81920000);
  ushort* W1t  = (ushort*)(ws + oW1T);
  unsigned char* Yl8 = (unsigned char*)(ws + oYL8);
  ushort* Yrb  = (ushort*)(ws + oYRB);
  ushort* W2t  = (ushort*)(ws + oW2T);
  int*    srcs = (int*)   (ws + oSRC);
  int*    deg  = (int*)   (ws + oDEG);
  int*    mrk  = (int*)   (ws + oMRK);
  int*    rpt  = (int*)   (ws + oRPT);
  int*    cur  = (int*)   (ws + oCUR);
  ushort* Adb  = (ushort*)(ws + oADB);
  ushort* Wdt  = (ushort*)(ws + oWDT);
  ushort* xcat = (ushort*)(ws + oXC);
  ushort* W1rt = (ushort*)(ws + oW1R);
  ushort* W2rt = (ushort*)(ws + oW2R);
  ushort* h1   = (ushort*)(ws + oH1);
  ushort* h2   = (ushort*)(ws + oH2);

  const int* esrc = edges;
  const int* edst = edges + NEDGE;

  // deg + mrk are adjacent: one memset covers both
  hipMemsetAsync(deg, 0, (oMRK - oDEG) + (size_t)N_CELL * 4, stream);

  deg_mark<<<2064, 256, 0, stream>>>(edst, deg, cell, mrk);
  scan_kernel<<<1, 1024, 0, stream>>>(deg, rpt, cur, N_CELL);
  bucket_kernel<<<2048, 256, 0, stream>>>(esrc, edst, cur, srcs, NEDGE);

  conv_xd<<<(N_CELL * (D_CELL_P / 8)) / 256 + (BATCH * (D_DRUG / 8)) / 256, 256, 0, stream>>>(
      cell_x, drug_x, drug, Xb, Adb);
  conv_wt_all<<<7888, 256, 0, stream>>>(c1_lW, c1_rW, c2_lW, c2_rW, demb_W, reg_W1, reg_W2,
                                        W1t, W2t, Wdt, W1rt, W2rt);

  gemm2p<0, D_CELL_P><<<dim3(2048 / 128, (N_CELL + 255) / 256), 512, 0, stream>>>(
      Xb, W1t, (float*)Yl8, Yrb, N_CELL);
  agg1_c1<<<(N_CELL / 4) * 8, 256, 0, stream>>>(Yl8, Yrb, c1_lb, rpt, srcs, c1b);

  gemm2p<1, 1024><<<dim3(512 / 128, (N_CELL + 255) / 256), 512, 0, stream>>>(
      c1b, W2t, nullptr, Zb, N_CELL);
  agg2_c2<<<N_CELL, 256, 0, stream>>>(Zb, c2_lb, rpt, srcs, mrk, c2v);

  gemm_bt<2><<<dim3(1, BATCH / 128), 256, 0, stream>>>(
      Adb, Wdt, nullptr, xcat, demb_b, BATCH, 128, 384, 384);
  xcat2<<<(BATCH * 64) / 256, 256, 0, stream>>>(c2v, cell, xcat);

  gemm_bt<3><<<dim3(384 / 128, BATCH / 128), 256, 0, stream>>>(
      xcat, W1rt, nullptr, h1, reg_b1, BATCH, 384, 384, 384);
  gemm_bt<3><<<dim3(384 / 128, BATCH / 128), 256, 0, stream>>>(
      h1, W2rt, nullptr, h2, reg_b2, BATCH, 384, 384, 384);
  final_k<<<BATCH / 4, 256, 0, stream>>>(h2, reg_W3, reg_b3, out);
}

// Round 15
// 797.100 us; speedup vs baseline: 1.0644x; 1.0644x over previous
//
#include <hip/hip_runtime.h>
#include <hip/hip_bf16.h>

typedef __bf16 bf16x8 __attribute__((ext_vector_type(8)));
typedef float f32x4 __attribute__((ext_vector_type(4)));
typedef float f32x2 __attribute__((ext_vector_type(2)));
typedef unsigned short u16x8 __attribute__((ext_vector_type(8)));

#define N_DRUG   10000
#define N_CELL   20000
#define NEDGE    1280000
#define D_DRUG   384
#define D_CELL   3504
#define D_CELL_P 3520
#define BATCH    4096

typedef unsigned int u32_g __attribute__((address_space(1)));
typedef unsigned int u32_l __attribute__((address_space(3)));

__device__ __forceinline__ void gld_lds16(const void* g, void* l) {
  __builtin_amdgcn_global_load_lds((const u32_g*)g, (u32_l*)l, 16, 0, 0);
}

__device__ __forceinline__ ushort f2bf(float f) {
  union { float f; unsigned u; } v; v.f = f;
  unsigned r = v.u + 0x7fffu + ((v.u >> 16) & 1u);
  return (ushort)(r >> 16);
}
__device__ __forceinline__ float bf2f(ushort h) {
  union { unsigned u; float f; } v; v.u = ((unsigned)h) << 16;
  return v.f;
}

#define S_BARRIER() asm volatile("s_barrier" ::: "memory")
#define VMCNT6()    asm volatile("s_waitcnt vmcnt(6)" ::: "memory")
#define VMCNT0()    asm volatile("s_waitcnt vmcnt(0)" ::: "memory")

// ---------------- fused conversions ----------------

__global__ __launch_bounds__(256) void conv_xd(const float* __restrict__ x,
                                               const float* __restrict__ dx,
                                               const int* __restrict__ drug,
                                               ushort* __restrict__ xb,
                                               ushort* __restrict__ adb) {
  const int CXB = (N_CELL * (D_CELL_P / 8)) / 256;   // 34375
  if (blockIdx.x < CXB) {
    int idx = blockIdx.x * 256 + threadIdx.x;
    const int CH = D_CELL_P / 8;
    int r = idx / CH, c8 = (idx % CH) * 8;
    if (r >= N_CELL) return;
    ushort4 a, b;
    if (c8 < D_CELL) {
      const float* p = x + (size_t)r * D_CELL + c8;
      float4 v0 = *(const float4*)p;
      float4 v1 = *(const float4*)(p + 4);
      a = make_ushort4(f2bf(v0.x), f2bf(v0.y), f2bf(v0.z), f2bf(v0.w));
      b = make_ushort4(f2bf(v1.x), f2bf(v1.y), f2bf(v1.z), f2bf(v1.w));
    } else {
      a = make_ushort4(0,0,0,0); b = make_ushort4(0,0,0,0);
    }
    ushort* q = xb + (size_t)r * D_CELL_P + c8;
    *(ushort4*)q = a; *(ushort4*)(q + 4) = b;
  } else {
    int idx = (blockIdx.x - CXB) * 256 + threadIdx.x;
    int r = idx / 48, c8 = (idx % 48) * 8;
    int g = drug[r];
    const float* p = dx + (size_t)g * D_DRUG + c8;
    float4 v0 = *(const float4*)p, v1 = *(const float4*)(p + 4);
    ushort4 a = make_ushort4(f2bf(v0.x), f2bf(v0.y), f2bf(v0.z), f2bf(v0.w));
    ushort4 b = make_ushort4(f2bf(v1.x), f2bf(v1.y), f2bf(v1.z), f2bf(v1.w));
    ushort* q = adb + (size_t)r * D_DRUG + c8;
    *(ushort4*)q = a; *(ushort4*)(q + 4) = b;
  }
}

__global__ __launch_bounds__(256) void conv_wt_all(
    const float* __restrict__ c1_lW, const float* __restrict__ c1_rW,
    const float* __restrict__ c2_lW, const float* __restrict__ c2_rW,
    const float* __restrict__ demb_W, const float* __restrict__ reg_W1,
    const float* __restrict__ reg_W2,
    ushort* __restrict__ W1t, ushort* __restrict__ W2t, ushort* __restrict__ Wdt,
    ushort* __restrict__ W1rt, ushort* __restrict__ W2rt) {
  int id = blockIdx.x;
  const float *L, *R; int nL, N, Kin, Kp, nkx; ushort* out; int base;
  if (id < 7040)      { base = 0;    L = c1_lW;  R = c1_rW;  nL = 1024; N = 2048; Kin = 3504; Kp = 3520; out = W1t;  nkx = 110; }
  else if (id < 7552) { base = 7040; L = c2_lW;  R = c2_rW;  nL = 256;  N = 512;  Kin = 1024; Kp = 1024; out = W2t;  nkx = 32; }
  else if (id < 7600) { base = 7552; L = demb_W; R = demb_W; nL = 128;  N = 128;  Kin = 384;  Kp = 384;  out = Wdt;  nkx = 12; }
  else if (id < 7744) { base = 7600; L = reg_W1; R = reg_W1; nL = 384;  N = 384;  Kin = 384;  Kp = 384;  out = W1rt; nkx = 12; }
  else                { base = 7744; L = reg_W2; R = reg_W2; nL = 384;  N = 384;  Kin = 384;  Kp = 384;  out = W2rt; nkx = 12; }
  int lid = id - base;
  int k0 = (lid % nkx) * 32, n0 = (lid / nkx) * 32;

  __shared__ float tile[32][33];
  int t = threadIdx.x;
  int tn = t & 31, tk = t >> 5;
  #pragma unroll
  for (int p = 0; p < 4; ++p) {
    int k = k0 + tk + p * 8, n = n0 + tn;
    float v = 0.f;
    if (k < Kin) v = (n < nL) ? L[(size_t)k * nL + n] : R[(size_t)k * (N - nL) + (n - nL)];
    tile[tk + p * 8][tn] = v;
  }
  __syncthreads();
  int wk = t & 31, wn = t >> 5;
  #pragma unroll
  for (int p = 0; p < 4; ++p) {
    int n = n0 + wn + p * 8, k = k0 + wk;
    out[(size_t)n * Kp + k] = f2bf(tile[wk][wn + p * 8]);
  }
}

// ---------------- CSR build ----------------

__global__ void deg_mark(const int* __restrict__ dst, int* __restrict__ deg,
                         const int* __restrict__ cell, int* __restrict__ mark) {
  if (blockIdx.x < 2048) {
    for (int e = blockIdx.x * 256 + threadIdx.x; e < NEDGE; e += 2048 * 256)
      atomicAdd(&deg[dst[e]], 1);
  } else {
    int b = (blockIdx.x - 2048) * 256 + threadIdx.x;
    if (b < BATCH) mark[cell[b]] = 1;
  }
}

__global__ __launch_bounds__(1024) void scan_kernel(const int* __restrict__ deg,
                                                    int* __restrict__ rowptr,
                                                    int* __restrict__ cursor, int n) {
  __shared__ int wsum[16];
  __shared__ int carry_s;
  int t = threadIdx.x, wave = t >> 6, lane = t & 63;
  if (t == 0) carry_s = 0;
  __syncthreads();
  for (int base = 0; base < n; base += 1024) {
    int x = (base + t < n) ? deg[base + t] : 0;
    int v = x;
    #pragma unroll
    for (int off = 1; off < 64; off <<= 1) {
      int u = __shfl_up(v, off, 64);
      if (lane >= off) v += u;
    }
    if (lane == 63) wsum[wave] = v;
    __syncthreads();
    if (wave == 0 && lane < 16) {
      int w = wsum[lane];
      #pragma unroll
      for (int off = 1; off < 16; off <<= 1) {
        int u = __shfl_up(w, off, 64);
        if (lane >= off) w += u;
      }
      wsum[lane] = w;
    }
    __syncthreads();
    int wpre = (wave == 0) ? 0 : wsum[wave - 1];
    int incl = v + wpre;
    int carry = carry_s;
    if (base + t < n) { int ex = carry + incl - x; rowptr[base + t] = ex; cursor[base + t] = ex; }
    __syncthreads();
    if (t == 1023) carry_s = carry + incl;
    __syncthreads();
  }
  if (t == 0) rowptr[n] = carry_s;
}

__global__ void bucket_kernel(const int* __restrict__ src, const int* __restrict__ dst,
                              int* __restrict__ cursor, int* __restrict__ srcs, int n) {
  for (int e = blockIdx.x * blockDim.x + threadIdx.x; e < n; e += gridDim.x * blockDim.x) {
    int p = atomicAdd(&cursor[dst[e]], 1);
    srcs[p] = src[e];
  }
}

// ---------------- 256x256 GEMM, 16x16x32, 4-phase, vmcnt(6)@P4 ----------------
// K is a COMPILE-TIME template param (r9 regression: runtime K cost 36us).
// Grid mapping: blockIdx.x = COL tile, blockIdx.y = ROW tile (r11 proven).
// EPI 0 (GEMM1): col<1024 -> fp8 e4m3 (agg operand); col>=1024 -> bf16 (root).
// EPI 1 (GEMM2): outB bf16 [M,512].
template <int EPI, int K>
__global__ __launch_bounds__(512, 2) void gemm8p(const ushort* __restrict__ A,
                                                 const ushort* __restrict__ Bt,
                                                 float* __restrict__ outF,
                                                 ushort* __restrict__ outB,
                                                 int M) {
  constexpr int NK = K / 64;
  __shared__ ushort lds[2][2][32][512];  // [buf][A/B][chunk 16rx32c][slot] = 128KB

  const int t = threadIdx.x;
  const int wid = t >> 6, lane = t & 63;
  const int wr = wid >> 2, wc = wid & 3;
  const int brow = blockIdx.y * 256, bcol = blockIdx.x * 256;
  const int fr = lane & 15, kgi = lane >> 4;
  const int slot8 = (fr * 4 + (kgi ^ ((fr >> 1) & 3))) * 8;
  const int srow = lane >> 2;
  const int gsw = ((lane & 3) ^ ((lane >> 3) & 3)) * 8;

  f32x4 acc[8][4];
  #pragma unroll
  for (int m = 0; m < 8; ++m)
    #pragma unroll
    for (int n = 0; n < 4; ++n) acc[m][n] = f32x4{0.f, 0.f, 0.f, 0.f};

  bf16x8 af[4][2], bfg[4][2];

  auto stage = [&](int b, int h, int kt) {   // h: 0=A0 1=A1 2=B0 3=B1
    const ushort* base = (h < 2) ? A : Bt;
    const int rb = (h < 2) ? brow : bcol;
    const int half = h & 1, ab = h >> 1;
    const int k0 = kt * 64;
    #pragma unroll
    for (int j = 0; j < 2; ++j) {
      int c = j * 8 + wid;                   // chunk within half (0..15)
      int r16 = half * 8 + (c >> 1), kc = c & 1;
      int row = rb + r16 * 16 + srow;
      if (h < 2) row = row < M ? row : M - 1;
      gld_lds16(base + (size_t)row * K + k0 + kc * 32 + gsw,
                &lds[b][ab][half * 16 + c][0]);
    }
  };

  stage(0, 0, 0); stage(0, 2, 0); stage(0, 3, 0); stage(0, 1, 0);
  stage(1, 0, 1); stage(1, 2, 1); stage(1, 3, 1);
  VMCNT6();
  S_BARRIER();

  for (int kt = 0; kt < NK; ++kt) {
    const int b = kt & 1, nb = b ^ 1;
    const bool dr = (kt >= NK - 2);

    // ---- P1: m0-3 x n0-1 ----
    #pragma unroll
    for (int m = 0; m < 4; ++m) {
      af[m][0] = *(const bf16x8*)&lds[b][0][(2 * m + wr) * 2 + 0][slot8];
      af[m][1] = *(const bf16x8*)&lds[b][0][(2 * m + wr) * 2 + 1][slot8];
    }
    #pragma unroll
    for (int n = 0; n < 2; ++n) {
      bfg[n][0] = *(const bf16x8*)&lds[b][1][(4 * n + wc) * 2 + 0][slot8];
      bfg[n][1] = *(const bf16x8*)&lds[b][1][(4 * n + wc) * 2 + 1][slot8];
    }
    if (kt + 1 < NK) stage(nb, 1, kt + 1);
    S_BARRIER();
    __builtin_amdgcn_s_setprio(1);
    #pragma unroll
    for (int m = 0; m < 4; ++m)
      #pragma unroll
      for (int n = 0; n < 2; ++n) {
        acc[m][n] = __builtin_amdgcn_mfma_f32_16x16x32_bf16(af[m][0], bfg[n][0], acc[m][n], 0, 0, 0);
        acc[m][n] = __builtin_amdgcn_mfma_f32_16x16x32_bf16(af[m][1], bfg[n][1], acc[m][n], 0, 0, 0);
      }
    __builtin_amdgcn_s_setprio(0);
    S_BARRIER();

    // ---- P2: m0-3 x n2-3 ----
    #pragma unroll
    for (int n = 2; n < 4; ++n) {
      bfg[n][0] = *(const bf16x8*)&lds[b][1][(4 * n + wc) * 2 + 0][slot8];
      bfg[n][1] = *(const bf16x8*)&lds[b][1][(4 * n + wc) * 2 + 1][slot8];
    }
    if (kt + 2 < NK) stage(b, 0, kt + 2);
    S_BARRIER();
    __builtin_amdgcn_s_setprio(1);
    #pragma unroll
    for (int m = 0; m < 4; ++m)
      #pragma unroll
      for (int n = 2; n < 4; ++n) {
        acc[m][n] = __builtin_amdgcn_mfma_f32_16x16x32_bf16(af[m][0], bfg[n][0], acc[m][n], 0, 0, 0);
        acc[m][n] = __builtin_amdgcn_mfma_f32_16x16x32_bf16(af[m][1], bfg[n][1], acc[m][n], 0, 0, 0);
      }
    __builtin_amdgcn_s_setprio(0);
    S_BARRIER();

    // ---- P3: m4-7 x n0-1 ----
    #pragma unroll
    for (int m = 0; m < 4; ++m) {
      af[m][0] = *(const bf16x8*)&lds[b][0][(2 * (m + 4) + wr) * 2 + 0][slot8];
      af[m][1] = *(const bf16x8*)&lds[b][0][(2 * (m + 4) + wr) * 2 + 1][slot8];
    }
    if (kt + 2 < NK) stage(b, 2, kt + 2);
    S_BARRIER();
    __builtin_amdgcn_s_setprio(1);
    #pragma unroll
    for (int m = 0; m < 4; ++m)
      #pragma unroll
      for (int n = 0; n < 2; ++n) {
        acc[m + 4][n] = __builtin_amdgcn_mfma_f32_16x16x32_bf16(af[m][0], bfg[n][0], acc[m + 4][n], 0, 0, 0);
        acc[m + 4][n] = __builtin_amdgcn_mfma_f32_16x16x32_bf16(af[m][1], bfg[n][1], acc[m + 4][n], 0, 0, 0);
      }
    __builtin_amdgcn_s_setprio(0);
    S_BARRIER();

    // ---- P4: m4-7 x n2-3 ----
    if (kt + 2 < NK) stage(b, 3, kt + 2);
    S_BARRIER();
    __builtin_amdgcn_s_setprio(1);
    #pragma unroll
    for (int m = 0; m < 4; ++m)
      #pragma unroll
      for (int n = 2; n < 4; ++n) {
        acc[m + 4][n] = __builtin_amdgcn_mfma_f32_16x16x32_bf16(af[m][0], bfg[n][0], acc[m + 4][n], 0, 0, 0);
        acc[m + 4][n] = __builtin_amdgcn_mfma_f32_16x16x32_bf16(af[m][1], bfg[n][1], acc[m + 4][n], 0, 0, 0);
      }
    __builtin_amdgcn_s_setprio(0);
    if (dr) { VMCNT0(); } else { VMCNT6(); }
    S_BARRIER();
  }

  unsigned char* o8 = (unsigned char*)outF;   // EPI 0: fp8 agg operand
  #pragma unroll
  for (int m = 0; m < 8; ++m)
    #pragma unroll
    for (int n = 0; n < 4; ++n)
      #pragma unroll
      for (int j = 0; j < 4; ++j) {
        int row = brow + (2 * m + wr) * 16 + kgi * 4 + j;
        int col = bcol + (4 * n + wc) * 16 + fr;
        if (row < M) {
          float v = acc[m][n][j];
          if constexpr (EPI == 0) {
            if (col < 1024) {
              int p = __builtin_amdgcn_cvt_pk_fp8_f32(v, v, 0, false);
              o8[(size_t)row * 1024 + col] = (unsigned char)(p & 0xff);
            } else {
              outB[(size_t)row * 1024 + (col - 1024)] = f2bf(v);
            }
          } else {
            outB[(size_t)row * 512 + col] = f2bf(v);
          }
        }
      }
}

// ---------------- 128x128 GEMM (small GEMMs) ----------------
template <int EPI>
__global__ __launch_bounds__(256) void gemm_bt(const ushort* __restrict__ A,
                                               const ushort* __restrict__ Bt,
                                               float* __restrict__ outF,
                                               ushort* __restrict__ outB,
                                               const float* __restrict__ bias,
                                               int M, int N, int K, int ldc) {
  __shared__ ushort ldsA[128 * 32];
  __shared__ ushort ldsB[128 * 32];
  const int t = threadIdx.x;
  const int wave = t >> 6, lane = t & 63;
  const int brow = blockIdx.y * 128;
  const int bcol = blockIdx.x * 128;
  const int wr = wave >> 1, wc = wave & 1;

  f32x4 acc[4][4];
  #pragma unroll
  for (int m = 0; m < 4; ++m)
    #pragma unroll
    for (int n = 0; n < 4; ++n) acc[m][n] = f32x4{0.f, 0.f, 0.f, 0.f};

  const int srow = lane >> 2;
  const int gsw  = ((lane & 3) ^ ((lane >> 3) & 3)) * 8;
  const int nk = K >> 5;

  const int fr = lane & 15;
  const int kgi = lane >> 4;
  const int slot = (fr * 4 + (kgi ^ ((fr >> 1) & 3))) * 8;

  for (int kt = 0; kt < nk; ++kt) {
    const int k0 = kt * 32;
    #pragma unroll
    for (int i = 0; i < 2; ++i) {
      int c = i * 4 + wave;
      int arow = brow + c * 16 + srow;
      arow = arow < M ? arow : M - 1;
      gld_lds16(A + (size_t)arow * K + k0 + gsw, ldsA + c * 512);
      int brB = bcol + c * 16 + srow;
      gld_lds16(Bt + (size_t)brB * K + k0 + gsw, ldsB + c * 512);
    }
    __syncthreads();
    bf16x8 af[4], bf[4];
    #pragma unroll
    for (int m = 0; m < 4; ++m) af[m] = *(const bf16x8*)(ldsA + (wr * 4 + m) * 512 + slot);
    #pragma unroll
    for (int n = 0; n < 4; ++n) bf[n] = *(const bf16x8*)(ldsB + (wc * 4 + n) * 512 + slot);
    #pragma unroll
    for (int m = 0; m < 4; ++m)
      #pragma unroll
      for (int n = 0; n < 4; ++n)
        acc[m][n] = __builtin_amdgcn_mfma_f32_16x16x32_bf16(af[m], bf[n], acc[m][n], 0, 0, 0);
    __syncthreads();
  }

  const int fq = lane >> 4;
  #pragma unroll
  for (int m = 0; m < 4; ++m) {
    #pragma unroll
    for (int n = 0; n < 4; ++n) {
      #pragma unroll
      for (int j = 0; j < 4; ++j) {
        int row = brow + wr * 64 + m * 16 + fq * 4 + j;
        int col = bcol + wc * 64 + n * 16 + fr;
        if (row < M) {
          float v = acc[m][n][j];
          if constexpr (EPI == 0) {
            outF[(size_t)row * ldc + col] = v;
          } else if constexpr (EPI == 2) {
            v += bias[col];
            v = fmaxf(v, 0.f);
            outB[(size_t)row * ldc + col] = f2bf(v);
          } else {
            v += bias[col];
            v = v > 0.f ? v : expm1f(v);
            outB[(size_t)row * ldc + col] = f2bf(v);
          }
        }
      }
    }
  }
}

// ---------------- aggregation ----------------

// layer 1, XCD-sliced, fp8 agg operand: block b handles slice s = b&7
// (128 cols = 128 B fp8, 2.56MB/XCD slice -> L2-resident) of 4 nodes (one
// per wave). 8 edge-groups x 8 lanes x 16B. Root path from bf16 Yrb.
__global__ __launch_bounds__(256) void agg1_c1(const unsigned char* __restrict__ Yl8,
                                               const ushort* __restrict__ Yrb,
                                               const float* __restrict__ lb,
                                               const int* __restrict__ rowptr,
                                               const int* __restrict__ srcs,
                                               ushort* __restrict__ c1b) {
  const int b = blockIdx.x, t = threadIdx.x;
  const int s = b & 7;                       // column slice (XCD-pinned)
  const int i = (b >> 3) * 4 + (t >> 6);     // node
  const int lane = t & 63;
  const int eg = lane >> 3, c8 = lane & 7;   // 8 edge groups x 16-col chunks
  const int s0 = rowptr[i], s1 = rowptr[i + 1];
  const unsigned char* base = Yl8 + s * 128 + c8 * 16;

  float a[16];
  #pragma unroll
  for (int k = 0; k < 16; ++k) a[k] = 0.f;

  auto accum = [&](uint4 v) {
    const unsigned* w = (const unsigned*)&v;
    #pragma unroll
    for (int q = 0; q < 4; ++q) {
      f32x2 lo = __builtin_amdgcn_cvt_pk_f32_fp8(w[q], false);
      f32x2 hi = __builtin_amdgcn_cvt_pk_f32_fp8(w[q], true);
      a[q * 4 + 0] += lo.x; a[q * 4 + 1] += lo.y;
      a[q * 4 + 2] += hi.x; a[q * 4 + 3] += hi.y;
    }
  };

  int e = s0 + eg;
  for (; e + 8 < s1; e += 16) {
    uint4 vA = *(const uint4*)(base + (size_t)srcs[e] * 1024);
    uint4 vB = *(const uint4*)(base + (size_t)srcs[e + 8] * 1024);
    accum(vA); accum(vB);
  }
  for (; e < s1; e += 8) {
    uint4 v = *(const uint4*)(base + (size_t)srcs[e] * 1024);
    accum(v);
  }
  #pragma unroll
  for (int k = 0; k < 16; ++k) {
    a[k] += __shfl_xor(a[k], 8, 64);
    a[k] += __shfl_xor(a[k], 16, 64);
    a[k] += __shfl_xor(a[k], 32, 64);
  }
  if (eg == 0) {
    float inv = 1.0f / fmaxf((float)(s1 - s0), 1.0f);
    size_t off = (size_t)i * 1024 + s * 128 + c8 * 16;
    u16x8 r0 = *(const u16x8*)(Yrb + off);
    u16x8 r1 = *(const u16x8*)(Yrb + off + 8);
    u16x8 o0, o1;
    #pragma unroll
    for (int k = 0; k < 8; ++k) {
      float v0 = a[k] * inv + lb[s * 128 + c8 * 16 + k] + bf2f(r0[k]);
      float v1 = a[k + 8] * inv + lb[s * 128 + c8 * 16 + 8 + k] + bf2f(r1[k]);
      o0[k] = f2bf(fmaxf(v0, 0.f));
      o1[k] = f2bf(fmaxf(v1, 0.f));
    }
    *(u16x8*)(c1b + off) = o0;
    *(u16x8*)(c1b + off + 8) = o1;
  }
}

// layer 2 (marked nodes only), bf16 Z [20000 x 512]
__global__ __launch_bounds__(256) void agg2_c2(const ushort* __restrict__ Zb,
                                               const float* __restrict__ lb,
                                               const int* __restrict__ rowptr,
                                               const int* __restrict__ srcs,
                                               const int* __restrict__ mark,
                                               ushort* __restrict__ c2v) {
  int i = blockIdx.x;
  if (!mark[i]) return;
  __shared__ float red[4][32][8];
  int t = threadIdx.x;
  int sub = t >> 5, c = t & 31;
  int wave = t >> 6, lane = t & 63;
  int s0 = rowptr[i], s1 = rowptr[i + 1];
  float a[8] = {0.f, 0.f, 0.f, 0.f, 0.f, 0.f, 0.f, 0.f};
  int e = s0 + sub;
  for (; e + 8 < s1; e += 16) {
    int sA = srcs[e], sB = srcs[e + 8];
    u16x8 vA = *(const u16x8*)(Zb + (size_t)sA * 512 + c * 8);
    u16x8 vB = *(const u16x8*)(Zb + (size_t)sB * 512 + c * 8);
    #pragma unroll
    for (int k = 0; k < 8; ++k) a[k] += bf2f(vA[k]) + bf2f(vB[k]);
  }
  for (; e < s1; e += 8) {
    int src = srcs[e];
    u16x8 v = *(const u16x8*)(Zb + (size_t)src * 512 + c * 8);
    #pragma unroll
    for (int k = 0; k < 8; ++k) a[k] += bf2f(v[k]);
  }
  #pragma unroll
  for (int k = 0; k < 8; ++k) a[k] += __shfl_xor(a[k], 32, 64);
  if (lane < 32) {
    #pragma unroll
    for (int k = 0; k < 8; ++k) red[wave][lane][k] = a[k];
  }
  __syncthreads();
  if (t < 32) {
    float inv = 1.0f / fmaxf((float)(s1 - s0), 1.0f);
    u16x8 r = *(const u16x8*)(Zb + (size_t)i * 512 + 256 + t * 8);
    u16x8 o;
    #pragma unroll
    for (int k = 0; k < 8; ++k) {
      float sum = red[0][t][k] + red[1][t][k] + red[2][t][k] + red[3][t][k];
      float v = sum * inv + lb[t * 8 + k] + bf2f(r[k]);
      o[k] = f2bf(fmaxf(v, 0.f));
    }
    *(u16x8*)(c2v + (size_t)i * 256 + t * 8) = o;
  }
}

__global__ __launch_bounds__(256) void xcat2(const ushort* __restrict__ c2v,
                                             const int* __restrict__ cell,
                                             ushort* __restrict__ xcat) {
  int idx = blockIdx.x * 256 + threadIdx.x;
  int b = idx >> 6, q = idx & 63;
  ushort4 v = *(const ushort4*)(c2v + (size_t)cell[b] * 256 + q * 4);
  *(ushort4*)(xcat + (size_t)b * 384 + 128 + q * 4) = v;
}

__global__ __launch_bounds__(256) void final_k(const ushort* __restrict__ h2,
                                               const float* __restrict__ W3,
                                               const float* __restrict__ b3,
                                               float* __restrict__ out) {
  int row = blockIdx.x * 4 + (threadIdx.x >> 6);
  int lane = threadIdx.x & 63;
  const ushort* p = h2 + (size_t)row * 384;
  float s = 0.f;
  #pragma unroll
  for (int k = lane; k < 384; k += 64) s += bf2f(p[k]) * W3[k];
  #pragma unroll
  for (int off = 32; off; off >>= 1) s += __shfl_xor(s, off, 64);
  if (lane == 0) out[row] = s + b3[0];
}

// ---------------- launch ----------------

extern "C" void kernel_launch(void* const* d_in, const int* in_sizes, int n_in,
                              void* d_out, int out_size, void* d_ws, size_t ws_size,
                              hipStream_t stream) {
  (void)in_sizes; (void)n_in; (void)out_size; (void)ws_size;
  const int*   drug   = (const int*)  d_in[0];
  const int*   cell   = (const int*)  d_in[1];
  const float* drug_x = (const float*)d_in[2];
  const float* cell_x = (const float*)d_in[3];
  const int*   edges  = (const int*)  d_in[4];
  const float* demb_W = (const float*)d_in[5];
  const float* demb_b = (const float*)d_in[6];
  const float* c1_lW  = (const float*)d_in[7];
  const float* c1_lb  = (const float*)d_in[8];
  const float* c1_rW  = (const float*)d_in[9];
  const float* c2_lW  = (const float*)d_in[10];
  const float* c2_lb  = (const float*)d_in[11];
  const float* c2_rW  = (const float*)d_in[12];
  const float* reg_W1 = (const float*)d_in[13];
  const float* reg_b1 = (const float*)d_in[14];
  const float* reg_W2 = (const float*)d_in[15];
  const float* reg_b2 = (const float*)d_in[16];
  const float* reg_W3 = (const float*)d_in[17];
  const float* reg_b3 = (const float*)d_in[18];
  float* out = (float*)d_out;

  char* ws = (char*)d_ws;
  size_t off = 0;
  auto alloc = [&](size_t b) { size_t o = off; off += (b + 255) & ~(size_t)255; return o; };
  size_t oXB  = alloc((size_t)N_CELL * D_CELL_P * 2);
  size_t oW1T = alloc((size_t)2048 * D_CELL_P * 2);
  size_t oYL8 = alloc((size_t)N_CELL * 1024);          // fp8 agg operand
  size_t oYRB = alloc((size_t)N_CELL * 1024 * 2);      // bf16 root operand
  size_t oW2T = alloc((size_t)512 * 1024 * 2);
  size_t oSRC = alloc((size_t)NEDGE * 4);
  size_t oDEG = alloc((size_t)N_CELL * 4);
  size_t oMRK = alloc((size_t)N_CELL * 4);             // adjacent to deg
  size_t oRPT = alloc((size_t)(N_CELL + 1) * 4);
  size_t oCUR = alloc((size_t)N_CELL * 4);
  size_t oADB = alloc((size_t)BATCH * D_DRUG * 2);
  size_t oWDT = alloc((size_t)128 * 384 * 2);
  size_t oXC  = alloc((size_t)BATCH * 384 * 2);
  size_t oW1R = alloc((size_t)384 * 384 * 2);
  size_t oW2R = alloc((size_t)384 * 384 * 2);
  size_t oH1  = alloc((size_t)BATCH * 384 * 2);
  size_t oH2  = alloc((size_t)BATCH * 384 * 2);

  ushort* Xb   = (ushort*)(ws + oXB);
  ushort* c1b  = (ushort*)(ws + oXB);                   // after GEMM1, Xb dead
  ushort* Zb   = (ushort*)(ws + oXB + 40960000);        // bf16 [20000 x 512]
  ushort* c2v  = (ushort*)(ws + oXB + 81920000);
  ushort* W1t  = (ushort*)(ws + oW1T);
  unsigned char* Yl8 = (unsigned char*)(ws + oYL8);
  ushort* Yrb  = (ushort*)(ws + oYRB);
  ushort* W2t  = (ushort*)(ws + oW2T);
  int*    srcs = (int*)   (ws + oSRC);
  int*    deg  = (int*)   (ws + oDEG);
  int*    mrk  = (int*)   (ws + oMRK);
  int*    rpt  = (int*)   (ws + oRPT);
  int*    cur  = (int*)   (ws + oCUR);
  ushort* Adb  = (ushort*)(ws + oADB);
  ushort* Wdt  = (ushort*)(ws + oWDT);
  ushort* xcat = (ushort*)(ws + oXC);
  ushort* W1rt = (ushort*)(ws + oW1R);
  ushort* W2rt = (ushort*)(ws + oW2R);
  ushort* h1   = (ushort*)(ws + oH1);
  ushort* h2   = (ushort*)(ws + oH2);

  const int* esrc = edges;
  const int* edst = edges + NEDGE;

  // deg + mrk are adjacent: one memset covers both
  hipMemsetAsync(deg, 0, (oMRK - oDEG) + (size_t)N_CELL * 4, stream);

  deg_mark<<<2064, 256, 0, stream>>>(edst, deg, cell, mrk);
  scan_kernel<<<1, 1024, 0, stream>>>(deg, rpt, cur, N_CELL);
  bucket_kernel<<<2048, 256, 0, stream>>>(esrc, edst, cur, srcs, NEDGE);

  conv_xd<<<(N_CELL * (D_CELL_P / 8)) / 256 + (BATCH * (D_DRUG / 8)) / 256, 256, 0, stream>>>(
      cell_x, drug_x, drug, Xb, Adb);
  conv_wt_all<<<7888, 256, 0, stream>>>(c1_lW, c1_rW, c2_lW, c2_rW, demb_W, reg_W1, reg_W2,
                                        W1t, W2t, Wdt, W1rt, W2rt);

  gemm8p<0, D_CELL_P><<<dim3(2048 / 256, (N_CELL + 255) / 256), 512, 0, stream>>>(
      Xb, W1t, (float*)Yl8, Yrb, N_CELL);
  agg1_c1<<<(N_CELL / 4) * 8, 256, 0, stream>>>(Yl8, Yrb, c1_lb, rpt, srcs, c1b);

  gemm8p<1, 1024><<<dim3(512 / 256, (N_CELL + 255) / 256), 512, 0, stream>>>(
      c1b, W2t, nullptr, Zb, N_CELL);
  agg2_c2<<<N_CELL, 256, 0, stream>>>(Zb, c2_lb, rpt, srcs, mrk, c2v);

  gemm_bt<2><<<dim3(1, BATCH / 128), 256, 0, stream>>>(
      Adb, Wdt, nullptr, xcat, demb_b, BATCH, 128, 384, 384);
  xcat2<<<(BATCH * 64) / 256, 256, 0, stream>>>(c2v, cell, xcat);

  gemm_bt<3><<<dim3(384 / 128, BATCH / 128), 256, 0, stream>>>(
      xcat, W1rt, nullptr, h1, reg_b1, BATCH, 384, 384, 384);
  gemm_bt<3><<<dim3(384 / 128, BATCH / 128), 256, 0, stream>>>(
      h1, W2rt, nullptr, h2, reg_b2, BATCH, 384, 384, 384);
  final_k<<<BATCH / 4, 256, 0, stream>>>(h2, reg_W3, reg_b3, out);
}